// Round 6
// baseline (3049.548 us; speedup 1.0000x reference)
//
#include <hip/hip_runtime.h>

// MultiTaskGRUAttn: 2-layer bi-GRU (B=64,T=1024,D=64,H=128) + attn pooling + heads.
// fp32 inputs/outputs. Internals: f16 activations (x,gi,z), fp32 recurrent h,
// f16-pair weights in VGPRs with v_dot2_f32_f16, MFMA f16 input projections.
// ws: [f16 arena: x,wih0f,wih0b,wih1f,wih1b | z1 | z2 | gi chunk | hstate]

typedef unsigned short u16;
typedef _Float16 f16;
typedef f16  h2  __attribute__((ext_vector_type(2)));
typedef f16  h8  __attribute__((ext_vector_type(8)));
typedef float fv4 __attribute__((ext_vector_type(4)));

#if defined(__has_builtin)
#if __has_builtin(__builtin_amdgcn_fdot2)
#define HAVE_FDOT2 1
#endif
#endif

// ---------------------------------------------------------------------------
// Convert 5 fp32 tensors -> f16 arena (x, wih_l0f, wih_l0b, wih_l1f, wih_l1b).
// ---------------------------------------------------------------------------
struct Cvt5 { const float* src[5]; unsigned dst[5]; unsigned cum[6]; };

__global__ void cvt_f16(Cvt5 jb, f16* __restrict__ arena, unsigned total) {
  unsigned stride = gridDim.x * blockDim.x;
  for (unsigned idx = blockIdx.x * blockDim.x + threadIdx.x; idx < total; idx += stride) {
    int j = 0;
    while (idx >= jb.cum[j + 1]) j++;
    unsigned e = idx - jb.cum[j];
    arena[jb.dst[j] + e] = (f16)jb.src[j][e];
  }
}

// ---------------------------------------------------------------------------
// f16 MFMA input projection: gi[dir][ml][384] = A[g][K] @ W_dir^T + bias (fp32).
// ml local row, g = (ml>>lTc)*1024 + t0(dir) + (ml&(Tc-1)).
// grid (GB*Tc/64, 2), block 256: wave owns 16 rows x 24 N-tiles, K-step 32.
// m92-validated bt-GEMM frag pattern (A and W rows loaded identically);
// C/D: col=lane&15, row=quad*4+reg [m89]; layout dtype-independent [m121/m123].
// ---------------------------------------------------------------------------
__global__ __launch_bounds__(256) void proj_f16(
    const f16* __restrict__ A, const f16* __restrict__ Wf, const f16* __restrict__ Wb,
    const float* __restrict__ bf_, const float* __restrict__ bb_,
    f16* __restrict__ gi, int K, int t0f, int t0b, int lTc, int GB)
{
  const int N = 384;
  int Tc = 1 << lTc;
  int dir = blockIdx.y;
  const f16* __restrict__ W     = dir ? Wb  : Wf;
  const float* __restrict__ bias = dir ? bb_ : bf_;
  int t0 = dir ? t0b : t0f;
  f16* __restrict__ o = gi + (size_t)dir * GB * Tc * N;

  int lane = threadIdx.x & 63;
  int wv   = threadIdx.x >> 6;
  int mbase = blockIdx.x * 64 + wv * 16;
  int col  = lane & 15;
  int koff = (lane >> 4) * 8;

  int ml = mbase + col;                         // 16-row tile stays within one sample
  size_t g = (size_t)(ml >> lTc) * 1024 + t0 + (ml & (Tc - 1));
  const f16* ap = A + g * K + koff;             // A[m=lane&15][k=quad*8+j]
  const f16* wp = W + (size_t)col * K + koff;   // W rows: n=lane&15, k=quad*8+j

  fv4 acc[24];
#pragma unroll
  for (int i = 0; i < 24; i++) acc[i] = (fv4){0.f, 0.f, 0.f, 0.f};

  for (int kk = 0; kk < K; kk += 32) {
    h8 a = *(const h8*)(ap + kk);
#pragma unroll
    for (int nt = 0; nt < 24; nt++) {
      h8 bfrag = *(const h8*)(wp + (size_t)nt * 16 * K + kk);
      acc[nt] = __builtin_amdgcn_mfma_f32_16x16x32_f16(a, bfrag, acc[nt], 0, 0, 0);
    }
  }
  int rowq = (lane >> 4) * 4;
#pragma unroll
  for (int nt = 0; nt < 24; nt++) {
    int n = nt * 16 + col;
    float bs = bias[n];
#pragma unroll
    for (int r = 0; r < 4; r++) {
      size_t m = (size_t)(mbase + rowq + r);
      o[m * N + n] = (f16)(acc[nt][r] + bs);
    }
  }
}

// ---------------------------------------------------------------------------
// GRU recurrence, one block per sample handling BOTH dirs (512 thr = 8 waves):
// dir = tid>>8, unit i = tid&127, K-half = (tid>>7)&1.
// Weights as f16 pairs in VGPRs (96 dwords); h fp32 in-reg, broadcast copy f16
// in LDS; per step each wave does 1 ds_read_b32 + 32 readlane + 96 v_dot2.
// ---------------------------------------------------------------------------
__global__ __launch_bounds__(512, 2) void gru_recur(
    const float* __restrict__ whhf, const float* __restrict__ whhb,
    const float* __restrict__ bhhf, const float* __restrict__ bhhb,
    const f16* __restrict__ gi, f16* __restrict__ zout,
    float* __restrict__ hstate, int t0f, int t0b, int first, int Tc, int GB)
{
  const int H = 128, G = 384;
  int tid  = threadIdx.x;
  int dir  = tid >> 8;
  int i    = tid & 127;
  int half = (tid >> 7) & 1;
  int b    = blockIdx.x;
  const float* __restrict__ whh = dir ? whhb : whhf;
  const float* __restrict__ bhh = dir ? bhhb : bhhf;
  int t0 = dir ? t0b : t0f;

  // Pack Whh rows {i, H+i, 2H+i}, cols [half*64, +64) into f16 pairs (96 VGPRs).
  h2 wr2[32], wz2[32], wn2[32];
  {
    const float* pr = whh + (size_t)i * H + half * 64;
    const float* pz = whh + (size_t)(H + i) * H + half * 64;
    const float* pn = whh + (size_t)(2 * H + i) * H + half * 64;
#pragma unroll
    for (int k = 0; k < 64; k += 4) {
      float4 vr = *(const float4*)(pr + k);
      float4 vz = *(const float4*)(pz + k);
      float4 vn = *(const float4*)(pn + k);
      wr2[k/2]     = (h2){(f16)vr.x, (f16)vr.y};
      wr2[k/2 + 1] = (h2){(f16)vr.z, (f16)vr.w};
      wz2[k/2]     = (h2){(f16)vz.x, (f16)vz.y};
      wz2[k/2 + 1] = (h2){(f16)vz.z, (f16)vz.w};
      wn2[k/2]     = (h2){(f16)vn.x, (f16)vn.y};
      wn2[k/2 + 1] = (h2){(f16)vn.z, (f16)vn.w};
    }
  }
  float br = bhh[i], bz = bhh[H + i], bn = bhh[2 * H + i];

  __shared__ __align__(16) f16 hbuf2[2][2][128];   // [dir][dbuf][unit]
  __shared__ float pbuf[2][128][3];                // [dir][unit][gate]

  float* hs = hstate + (size_t)(dir * GB + b) * H;
  float h = 0.f;
  if (half == 0) {
    if (!first) h = hs[i];
    hbuf2[dir][0][i] = (f16)h;
  }

  const f16* girow = gi + (size_t)(dir * GB + b) * Tc * G;   // [tt][384] f16
  f16 r0r = (f16)0.f, r0z = (f16)0.f, r0n = (f16)0.f;
  f16 r1r = (f16)0.f, r1z = (f16)0.f, r1n = (f16)0.f;
  if (half == 0) {
    int tt0 = dir ? (Tc - 1) : 0;
    int tt1 = dir ? (Tc - 2) : 1;
    r0r = girow[(size_t)tt0 * G + i];
    r0z = girow[(size_t)tt0 * G + H + i];
    r0n = girow[(size_t)tt0 * G + 2 * H + i];
    r1r = girow[(size_t)tt1 * G + i];
    r1z = girow[(size_t)tt1 * G + H + i];
    r1n = girow[(size_t)tt1 * G + 2 * H + i];
  }
  __syncthreads();

  int lane = tid & 63;
  const int* hb[2] = { (const int*)&hbuf2[dir][0][0], (const int*)&hbuf2[dir][1][0] };
  int hidx = half * 32 + (lane & 31);              // dword index of h-pair (lanes 0-31 cover)

  for (int s = 0; s < Tc; s++) {
    int cur = s & 1;
    f16 n2r = (f16)0.f, n2z = (f16)0.f, n2n = (f16)0.f;
    if (half == 0 && s < Tc - 2) {                 // prefetch gi for step s+2
      int tt2 = dir ? (Tc - 3 - s) : (s + 2);
      const f16* gp = girow + (size_t)tt2 * G;
      n2r = gp[i]; n2z = gp[H + i]; n2n = gp[2 * H + i];
    }
    int hv = hb[cur][hidx];                        // 1 ds_read_b32 per lane
    float ar = 0.f, az = 0.f, an = 0.f;
#pragma unroll
    for (int k = 0; k < 32; k++) {
      int si = __builtin_amdgcn_readlane(hv, k);   // wave-uniform h pair -> SGPR
      h2 sh; __builtin_memcpy(&sh, &si, 4);
#if HAVE_FDOT2
      ar = __builtin_amdgcn_fdot2(wr2[k], sh, ar, false);
      az = __builtin_amdgcn_fdot2(wz2[k], sh, az, false);
      an = __builtin_amdgcn_fdot2(wn2[k], sh, an, false);
#else
      float s0 = (float)sh[0], s1 = (float)sh[1];
      ar = fmaf((float)wr2[k][0], s0, ar); ar = fmaf((float)wr2[k][1], s1, ar);
      az = fmaf((float)wz2[k][0], s0, az); az = fmaf((float)wz2[k][1], s1, az);
      an = fmaf((float)wn2[k][0], s0, an); an = fmaf((float)wn2[k][1], s1, an);
#endif
    }
    if (half == 1) { pbuf[dir][i][0] = ar; pbuf[dir][i][1] = az; pbuf[dir][i][2] = an; }
    __syncthreads();
    if (half == 0) {
      int tt = dir ? (Tc - 1 - s) : s;
      int t_abs = t0 + tt;
      float grh = ar + pbuf[dir][i][0] + br;
      float gzh = az + pbuf[dir][i][1] + bz;
      float gnh = an + pbuf[dir][i][2] + bn;
      float rg = 1.f / (1.f + __expf(-((float)r0r + grh)));
      float zg = 1.f / (1.f + __expf(-((float)r0z + gzh)));
      float npre = (float)r0n + rg * gnh;
      float e  = __expf(-2.f * fabsf(npre));       // tanh, overflow-safe
      float nv = (1.f - e) / (1.f + e);
      nv = (npre < 0.f) ? -nv : nv;
      h = nv + zg * (h - nv);                      // (1-z)*n + z*h
      hbuf2[dir][cur ^ 1][i] = (f16)h;
      zout[((size_t)b * 1024 + t_abs) * 256 + dir * H + i] = (f16)h;
      r0r = r1r; r0z = r1z; r0n = r1n;
      r1r = n2r; r1z = n2z; r1n = n2n;
    }
    __syncthreads();
  }
  if (half == 0) hs[i] = h;                        // fp32 carry to next chunk
}

// ---------------------------------------------------------------------------
// Attention pooling + heads (f16 z2 in, fp32 out). One block per sample.
// ---------------------------------------------------------------------------
__global__ __launch_bounds__(256) void pool_heads(
    const f16* __restrict__ z2, const float* __restrict__ attn_w, const float* __restrict__ attn_b,
    const float* __restrict__ motor_w, const float* __restrict__ motor_b,
    const float* __restrict__ state_w, const float* __restrict__ state_b,
    const int* __restrict__ motor_k, float* __restrict__ out, int bbase)
{
  const int T = 1024, D2 = 256;
  int bl = blockIdx.x;
  int babs = bbase + bl;
  const f16* Z = z2 + (size_t)bl * T * D2;
  __shared__ float sc[1024];
  __shared__ float red[8];
  __shared__ float pooled[256];
  int tid = threadIdx.x, lane = tid & 63, wv = tid >> 6;

  float aw0 = attn_w[lane],       aw1 = attn_w[64 + lane];
  float aw2 = attn_w[128 + lane], aw3 = attn_w[192 + lane];
  float ab = attn_b[0];
  for (int t = wv; t < T; t += 4) {
    const f16* zr = Z + (size_t)t * D2;
    float s = (float)zr[lane] * aw0 + (float)zr[64 + lane] * aw1
            + (float)zr[128 + lane] * aw2 + (float)zr[192 + lane] * aw3;
#pragma unroll
    for (int off = 32; off; off >>= 1) s += __shfl_down(s, off);
    if (lane == 0) sc[t] = s + ab;
  }
  __syncthreads();

  float m = -3.0e38f;
  for (int t = tid; t < T; t += 256) m = fmaxf(m, sc[t]);
#pragma unroll
  for (int off = 32; off; off >>= 1) m = fmaxf(m, __shfl_down(m, off));
  if (lane == 0) red[wv] = m;
  __syncthreads();
  m = fmaxf(fmaxf(red[0], red[1]), fmaxf(red[2], red[3]));
  float sum = 0.f;
  for (int t = tid; t < T; t += 256) { float e = __expf(sc[t] - m); sc[t] = e; sum += e; }
#pragma unroll
  for (int off = 32; off; off >>= 1) sum += __shfl_down(sum, off);
  if (lane == 0) red[4 + wv] = sum;
  __syncthreads();
  float S = red[4] + red[5] + red[6] + red[7];
  float inv = 1.f / S;

  float acc = 0.f;
  for (int t = 0; t < T; t++) acc = fmaf(sc[t], (float)Z[(size_t)t * D2 + tid], acc);
  pooled[tid] = acc * inv;
  __syncthreads();

  int o = tid >> 5, sl = tid & 31;
  if (o < 7) {
    int mk = motor_k[babs];
    const float* wp; float bias;
    if (o < 5) { wp = motor_w + o * D2;                          bias = motor_b[o]; }
    else       { wp = state_w + ((size_t)mk * 2 + (o - 5)) * D2; bias = state_b[mk * 2 + (o - 5)]; }
    float s = 0.f;
    for (int d = sl; d < D2; d += 32) s += pooled[d] * wp[d];
#pragma unroll
    for (int off = 16; off; off >>= 1) s += __shfl_down(s, off);
    if (sl == 0) {
      float v = s + bias;
      if (o < 5) out[babs * 5 + o] = v;
      else       out[320 + babs * 2 + (o - 5)] = v;
    }
  }
}

extern "C" void kernel_launch(void* const* d_in, const int* in_sizes, int n_in,
                              void* d_out, int out_size, void* d_ws, size_t ws_size,
                              hipStream_t stream) {
  const int* motor_k = (const int*)d_in[1];
  const float* whh_l0f = (const float*)d_in[3];
  const float* bih_l0f = (const float*)d_in[4];
  const float* bhh_l0f = (const float*)d_in[5];
  const float* whh_l0b = (const float*)d_in[7];
  const float* bih_l0b = (const float*)d_in[8];
  const float* bhh_l0b = (const float*)d_in[9];
  const float* whh_l1f = (const float*)d_in[11];
  const float* bih_l1f = (const float*)d_in[12];
  const float* bhh_l1f = (const float*)d_in[13];
  const float* whh_l1b = (const float*)d_in[15];
  const float* bih_l1b = (const float*)d_in[16];
  const float* bhh_l1b = (const float*)d_in[17];
  const float* attn_w  = (const float*)d_in[18];
  const float* attn_b  = (const float*)d_in[19];
  const float* motor_w = (const float*)d_in[20];
  const float* motor_b = (const float*)d_in[21];
  const float* state_w = (const float*)d_in[22];
  const float* state_b = (const float*)d_in[23];

  // f16 arena: x | wih_l0f | wih_l0b | wih_l1f | wih_l1b
  static const unsigned nel[5] = {4194304, 24576, 24576, 98304, 98304};
  static const int      idx[5] = {0, 2, 6, 10, 14};
  Cvt5 jb;
  unsigned cum = 0;
  unsigned dst[5];
  for (int j = 0; j < 5; j++) {
    jb.src[j] = (const float*)d_in[idx[j]];
    jb.cum[j] = cum; jb.dst[j] = cum; dst[j] = cum;
    cum += nel[j];
  }
  jb.cum[5] = cum;                                  // 4,440,064 elems
  f16* arena = (f16*)d_ws;
  size_t dynOffB = ((size_t)cum * 2 + 255) & ~(size_t)255;

  // Pick (batch-group GB, time-chunk Tc) to fit ws_size.
  static const int candGB[9] = {64,32,16,8,4,2,1,1,1};
  static const int candTc[9] = {256,256,256,256,256,256,256,128,64};
  int GB = 1, Tc = 64;
  for (int c = 0; c < 9; c++) {
    size_t nb = dynOffB
              + (size_t)candGB[c] * 1024 * 256 * 2 * 2              // z1+z2 f16
              + (size_t)2 * candGB[c] * candTc[c] * 384 * 2         // gi chunk f16
              + (size_t)2 * candGB[c] * 128 * 4;                    // hstate fp32
    if (nb <= ws_size) { GB = candGB[c]; Tc = candTc[c]; break; }
  }
  int lTc = 31 - __builtin_clz((unsigned)Tc);
  int nc = 1024 / Tc;

  f16* z1 = (f16*)((char*)d_ws + dynOffB);
  f16* z2 = z1 + (size_t)GB * 1024 * 256;
  f16* gi = z2 + (size_t)GB * 1024 * 256;
  float* hstate = (float*)(gi + (size_t)2 * GB * Tc * 384);

  const f16 *x16 = arena + dst[0], *w0f = arena + dst[1], *w0b = arena + dst[2],
            *w1f = arena + dst[3], *w1b = arena + dst[4];

  cvt_f16<<<1024, 256, 0, stream>>>(jb, arena, cum);

  dim3 gpb((unsigned)(GB * Tc / 64), 2, 1);
  for (int gb = 0; gb < 64 / GB; gb++) {
    const f16* xg = x16 + (size_t)gb * GB * 1024 * 64;
    for (int c = 0; c < nc; c++) {
      int t0f = c * Tc, t0b = (nc - 1 - c) * Tc;
      proj_f16<<<gpb, 256, 0, stream>>>(xg, w0f, w0b, bih_l0f, bih_l0b,
                                        gi, 64, t0f, t0b, lTc, GB);
      gru_recur<<<GB, 512, 0, stream>>>(whh_l0f, whh_l0b, bhh_l0f, bhh_l0b, gi, z1,
                                        hstate, t0f, t0b, c == 0, Tc, GB);
    }
    for (int c = 0; c < nc; c++) {
      int t0f = c * Tc, t0b = (nc - 1 - c) * Tc;
      proj_f16<<<gpb, 256, 0, stream>>>(z1, w1f, w1b, bih_l1f, bih_l1b,
                                        gi, 256, t0f, t0b, lTc, GB);
      gru_recur<<<GB, 512, 0, stream>>>(whh_l1f, whh_l1b, bhh_l1f, bhh_l1b, gi, z2,
                                        hstate, t0f, t0b, c == 0, Tc, GB);
    }
    pool_heads<<<GB, 256, 0, stream>>>(z2, attn_w, attn_b, motor_w, motor_b,
                                       state_w, state_b, motor_k, (float*)d_out, gb * GB);
  }
}

// Round 7
// 2924.733 us; speedup vs baseline: 1.0427x; 1.0427x over previous
//
#include <hip/hip_runtime.h>

// MultiTaskGRUAttn: 2-layer bi-GRU (B=64,T=1024,D=64,H=128) + attn pooling + heads.
// fp32 in/out. Internals: f16 activations (x,gi,z) + f16 MFMA matmuls, fp32 gates
// and fp32 recurrent h (in registers). Recurrence batched via MFMA: block = 16
// samples x 1 dir; wave w owns Whh B-frags for N-tiles {w,8+w,16+w} => its C tiles
// are exactly gates (r,z,n) of units [16w,16w+16) -- no cross-wave gate traffic.
// ws: [f16 arena: x,wih0f,wih0b,wih1f,wih1b | z1 | z2 | gi | hstate]

typedef unsigned short u16;
typedef _Float16 f16;
typedef f16  h8  __attribute__((ext_vector_type(8)));
typedef float fv4 __attribute__((ext_vector_type(4)));

#if defined(__has_builtin)
#if __has_builtin(__builtin_amdgcn_exp2f)
#define EXP2F(x) __builtin_amdgcn_exp2f(x)
#endif
#if __has_builtin(__builtin_amdgcn_rcpf)
#define RCPF(x) __builtin_amdgcn_rcpf(x)
#endif
#endif
#ifndef EXP2F
#define EXP2F(x) exp2f(x)
#endif
#ifndef RCPF
#define RCPF(x) (1.f / (x))
#endif

// ---------------------------------------------------------------------------
// Convert 5 fp32 tensors -> f16 arena (x, wih_l0f, wih_l0b, wih_l1f, wih_l1b).
// ---------------------------------------------------------------------------
struct Cvt5 { const float* src[5]; unsigned dst[5]; unsigned cum[6]; };

__global__ void cvt_f16(Cvt5 jb, f16* __restrict__ arena, unsigned total) {
  unsigned stride = gridDim.x * blockDim.x;
  for (unsigned idx = blockIdx.x * blockDim.x + threadIdx.x; idx < total; idx += stride) {
    int j = 0;
    while (idx >= jb.cum[j + 1]) j++;
    arena[jb.dst[j] + (idx - jb.cum[j])] = (f16)jb.src[j][idx - jb.cum[j]];
  }
}

// ---------------------------------------------------------------------------
// f16 MFMA input projection: gi[dir][ml][384] = A[g][K] @ W_dir^T + bias_eff.
// bias_eff = bih + (n<256 ? bhh : 0)  (r,z recurrent biases folded in; n-gate
// bias must stay in the recurrence: npre = i_n + r*(hW + bhh_n)).
// grid (64*Tc/64, 2), block 256: wave owns 16 rows x 24 N-tiles, K-step 32.
// m92 frag pattern; C/D col=lane&15, row=quad*4+reg [m89] (validated r3/r6).
// ---------------------------------------------------------------------------
__global__ __launch_bounds__(256) void proj_f16(
    const f16* __restrict__ A, const f16* __restrict__ Wf, const f16* __restrict__ Wb,
    const float* __restrict__ bihf, const float* __restrict__ bihb,
    const float* __restrict__ bhhf, const float* __restrict__ bhhb,
    f16* __restrict__ gi, int K, int t0f, int t0b, int lTc)
{
  const int N = 384;
  int Tc = 1 << lTc;
  int dir = blockIdx.y;
  const f16*   __restrict__ W   = dir ? Wb   : Wf;
  const float* __restrict__ bih = dir ? bihb : bihf;
  const float* __restrict__ bhh = dir ? bhhb : bhhf;
  int t0 = dir ? t0b : t0f;
  f16* __restrict__ o = gi + (size_t)dir * 64 * Tc * N;

  int lane = threadIdx.x & 63;
  int wv   = threadIdx.x >> 6;
  int mbase = blockIdx.x * 64 + wv * 16;
  int col  = lane & 15;
  int koff = (lane >> 4) * 8;

  int ml = mbase + col;
  size_t g = (size_t)(ml >> lTc) * 1024 + t0 + (ml & (Tc - 1));
  const f16* ap = A + g * K + koff;
  const f16* wp = W + (size_t)col * K + koff;

  fv4 acc[24];
#pragma unroll
  for (int i = 0; i < 24; i++) acc[i] = (fv4){0.f, 0.f, 0.f, 0.f};

  for (int kk = 0; kk < K; kk += 32) {
    h8 a = *(const h8*)(ap + kk);
#pragma unroll
    for (int nt = 0; nt < 24; nt++) {
      h8 bfrag = *(const h8*)(wp + (size_t)nt * 16 * K + kk);
      acc[nt] = __builtin_amdgcn_mfma_f32_16x16x32_f16(a, bfrag, acc[nt], 0, 0, 0);
    }
  }
  int rowq = (lane >> 4) * 4;
#pragma unroll
  for (int nt = 0; nt < 24; nt++) {
    int n = nt * 16 + col;
    float bs = bih[n] + ((n < 256) ? bhh[n] : 0.f);
#pragma unroll
    for (int r = 0; r < 4; r++) {
      size_t m = (size_t)(mbase + rowq + r);
      o[m * N + n] = (f16)(acc[nt][r] + bs);
    }
  }
}

// ---------------------------------------------------------------------------
// Batched-MFMA GRU recurrence. grid 8: block = (dir = blk>>2, samples b0=16*(blk&3)).
// 512 threads = 8 waves. Per step: gh[16][384] = h16[16][128] @ Whh^T via MFMA
// (wave w: tiles {w,8+w,16+w} = gates r,z,n of units 16w..16w+15, K=128 in 4 frags);
// then gate lanes (m=quad*4+r, n=16w+col) do fp32 gate math on their own
// accumulators, update fp32 h in registers, write f16 h to LDS for next MFMA.
// One __syncthreads per step (double-buffered h16).
// ---------------------------------------------------------------------------
__global__ __launch_bounds__(512) void gru_mfma(
    const float* __restrict__ whhf, const float* __restrict__ whhb,
    const float* __restrict__ bhhf, const float* __restrict__ bhhb,
    const f16* __restrict__ gi, f16* __restrict__ zout,
    float* __restrict__ hstate, int t0f, int t0b, int first, int Tc)
{
  const int H = 128;
  int dir = blockIdx.x >> 2;
  int b0  = (blockIdx.x & 3) << 4;
  const float* __restrict__ whh = dir ? whhb : whhf;
  const float* __restrict__ bhh = dir ? bhhb : bhhf;
  int t0 = dir ? t0b : t0f;

  int tid = threadIdx.x;
  int w = tid >> 6, lane = tid & 63;
  int col = lane & 15, quad = lane >> 4;
  int n = 16 * w + col;                       // unit owned in gate phase

  // Persistent B-fragments: B[k][nn] with nn=col of whh row (g*128 + 16w + col).
  h8 Bf[3][4];
#pragma unroll
  for (int g = 0; g < 3; g++) {
    const float* wrow = whh + (size_t)(g * 128 + n) * 128;
#pragma unroll
    for (int kf = 0; kf < 4; kf++) {
      const float* s = wrow + kf * 32 + quad * 8;
      float4 lo = *(const float4*)s, hi = *(const float4*)(s + 4);
      Bf[g][kf] = (h8){(f16)lo.x, (f16)lo.y, (f16)lo.z, (f16)lo.w,
                       (f16)hi.x, (f16)hi.y, (f16)hi.z, (f16)hi.w};
    }
  }
  float bn_ = bhh[256 + n];                   // n-gate recurrent bias (not folded)

  __shared__ __align__(16) f16 hsh[2][16][136];   // stride 136: 2-way banks (free)

  float hreg[4];                              // fp32 recurrent state, m = quad*4+r
#pragma unroll
  for (int r = 0; r < 4; r++) {
    int m = quad * 4 + r;
    hreg[r] = first ? 0.f : hstate[(size_t)(dir * 64 + b0 + m) * H + n];
    hsh[0][m][n] = (f16)hreg[r];
  }
  __syncthreads();

  int ttF = dir ? (Tc - 1) : 0;
  long gstep = dir ? -384 : 384;
  long zstep = dir ? -256 : 256;
  const f16* gp[4]; f16* zp[4];
#pragma unroll
  for (int r = 0; r < 4; r++) {
    int m = quad * 4 + r;
    gp[r] = gi + ((size_t)(dir * 64 + b0 + m) * Tc + ttF) * 384 + n;
    zp[r] = zout + ((size_t)(b0 + m) * 1024 + (t0 + ttF)) * 256 + dir * 128 + n;
  }
  f16 p0[4][3], p1[4][3];
#pragma unroll
  for (int r = 0; r < 4; r++) {
    p0[r][0] = gp[r][0]; p0[r][1] = gp[r][128]; p0[r][2] = gp[r][256];
    const f16* g1 = gp[r] + gstep;
    p1[r][0] = g1[0]; p1[r][1] = g1[128]; p1[r][2] = g1[256];
  }

  const float L2E = 1.4426950408889634f, L2E2 = 2.885390081777927f;

  for (int s = 0; s < Tc; s++) {
    int cur = s & 1;
    const f16* hb = (cur ? &hsh[1][0][0] : &hsh[0][0][0]) + col * 136 + quad * 8;
    fv4 a0 = {0.f,0.f,0.f,0.f}, a1 = {0.f,0.f,0.f,0.f}, a2 = {0.f,0.f,0.f,0.f};
#pragma unroll
    for (int kf = 0; kf < 4; kf++) {
      h8 a = *(const h8*)(hb + kf * 32);
      a0 = __builtin_amdgcn_mfma_f32_16x16x32_f16(a, Bf[0][kf], a0, 0, 0, 0);
      a1 = __builtin_amdgcn_mfma_f32_16x16x32_f16(a, Bf[1][kf], a1, 0, 0, 0);
      a2 = __builtin_amdgcn_mfma_f32_16x16x32_f16(a, Bf[2][kf], a2, 0, 0, 0);
    }
    f16 p2[4][3] = {};
    if (s < Tc - 2) {
#pragma unroll
      for (int r = 0; r < 4; r++) {
        const f16* g2 = gp[r] + 2 * gstep;
        p2[r][0] = g2[0]; p2[r][1] = g2[128]; p2[r][2] = g2[256];
      }
    }
    f16* hw = cur ? &hsh[0][0][0] : &hsh[1][0][0];
#pragma unroll
    for (int r = 0; r < 4; r++) {
      int m = quad * 4 + r;
      float ar = (float)p0[r][0] + a0[r];           // bih+bhh folded into gi
      float az = (float)p0[r][1] + a1[r];
      float xn = (float)p0[r][2];
      float gn = a2[r] + bn_;
      float rg = RCPF(1.f + EXP2F(-L2E * ar));
      float zg = RCPF(1.f + EXP2F(-L2E * az));
      float npre = fmaf(rg, gn, xn);
      float e = EXP2F(-L2E2 * fabsf(npre));
      float nv = (1.f - e) * RCPF(1.f + e);
      nv = copysignf(nv, npre);
      float h = nv + zg * (hreg[r] - nv);           // (1-z)*n + z*h
      hreg[r] = h;
      hw[m * 136 + n] = (f16)h;
      *zp[r] = (f16)h;
      p0[r][0] = p1[r][0]; p0[r][1] = p1[r][1]; p0[r][2] = p1[r][2];
      p1[r][0] = p2[r][0]; p1[r][1] = p2[r][1]; p1[r][2] = p2[r][2];
      gp[r] += gstep; zp[r] += zstep;
    }
    __syncthreads();
  }
#pragma unroll
  for (int r = 0; r < 4; r++) {
    int m = quad * 4 + r;
    hstate[(size_t)(dir * 64 + b0 + m) * H + n] = hreg[r];
  }
}

// ---------------------------------------------------------------------------
// Attention pooling + heads (f16 z2 in, fp32 out). One block per sample.
// ---------------------------------------------------------------------------
__global__ __launch_bounds__(256) void pool_heads(
    const f16* __restrict__ z2, const float* __restrict__ attn_w, const float* __restrict__ attn_b,
    const float* __restrict__ motor_w, const float* __restrict__ motor_b,
    const float* __restrict__ state_w, const float* __restrict__ state_b,
    const int* __restrict__ motor_k, float* __restrict__ out)
{
  const int T = 1024, D2 = 256;
  int b = blockIdx.x;
  const f16* Z = z2 + (size_t)b * T * D2;
  __shared__ float sc[1024];
  __shared__ float red[8];
  __shared__ float pooled[256];
  int tid = threadIdx.x, lane = tid & 63, wv = tid >> 6;

  float aw0 = attn_w[lane],       aw1 = attn_w[64 + lane];
  float aw2 = attn_w[128 + lane], aw3 = attn_w[192 + lane];
  float ab = attn_b[0];
  for (int t = wv; t < T; t += 4) {
    const f16* zr = Z + (size_t)t * D2;
    float s = (float)zr[lane] * aw0 + (float)zr[64 + lane] * aw1
            + (float)zr[128 + lane] * aw2 + (float)zr[192 + lane] * aw3;
#pragma unroll
    for (int off = 32; off; off >>= 1) s += __shfl_down(s, off);
    if (lane == 0) sc[t] = s + ab;
  }
  __syncthreads();

  float m = -3.0e38f;
  for (int t = tid; t < T; t += 256) m = fmaxf(m, sc[t]);
#pragma unroll
  for (int off = 32; off; off >>= 1) m = fmaxf(m, __shfl_down(m, off));
  if (lane == 0) red[wv] = m;
  __syncthreads();
  m = fmaxf(fmaxf(red[0], red[1]), fmaxf(red[2], red[3]));
  float sum = 0.f;
  for (int t = tid; t < T; t += 256) { float e = __expf(sc[t] - m); sc[t] = e; sum += e; }
#pragma unroll
  for (int off = 32; off; off >>= 1) sum += __shfl_down(sum, off);
  if (lane == 0) red[4 + wv] = sum;
  __syncthreads();
  float S = red[4] + red[5] + red[6] + red[7];
  float inv = 1.f / S;

  float acc = 0.f;
  for (int t = 0; t < T; t++) acc = fmaf(sc[t], (float)Z[(size_t)t * D2 + tid], acc);
  pooled[tid] = acc * inv;
  __syncthreads();

  int o = tid >> 5, sl = tid & 31;
  if (o < 7) {
    int mk = motor_k[b];
    const float* wp; float bias;
    if (o < 5) { wp = motor_w + o * D2;                          bias = motor_b[o]; }
    else       { wp = state_w + ((size_t)mk * 2 + (o - 5)) * D2; bias = state_b[mk * 2 + (o - 5)]; }
    float s = 0.f;
    for (int d = sl; d < D2; d += 32) s += pooled[d] * wp[d];
#pragma unroll
    for (int off = 16; off; off >>= 1) s += __shfl_down(s, off);
    if (sl == 0) {
      float v = s + bias;
      if (o < 5) out[b * 5 + o] = v;
      else       out[320 + b * 2 + (o - 5)] = v;
    }
  }
}

extern "C" void kernel_launch(void* const* d_in, const int* in_sizes, int n_in,
                              void* d_out, int out_size, void* d_ws, size_t ws_size,
                              hipStream_t stream) {
  const int* motor_k = (const int*)d_in[1];
  const float* whh_l0f = (const float*)d_in[3];
  const float* bih_l0f = (const float*)d_in[4];
  const float* bhh_l0f = (const float*)d_in[5];
  const float* whh_l0b = (const float*)d_in[7];
  const float* bih_l0b = (const float*)d_in[8];
  const float* bhh_l0b = (const float*)d_in[9];
  const float* whh_l1f = (const float*)d_in[11];
  const float* bih_l1f = (const float*)d_in[12];
  const float* bhh_l1f = (const float*)d_in[13];
  const float* whh_l1b = (const float*)d_in[15];
  const float* bih_l1b = (const float*)d_in[16];
  const float* bhh_l1b = (const float*)d_in[17];
  const float* attn_w  = (const float*)d_in[18];
  const float* attn_b  = (const float*)d_in[19];
  const float* motor_w = (const float*)d_in[20];
  const float* motor_b = (const float*)d_in[21];
  const float* state_w = (const float*)d_in[22];
  const float* state_b = (const float*)d_in[23];

  // f16 arena: x | wih_l0f | wih_l0b | wih_l1f | wih_l1b
  static const unsigned nel[5] = {4194304, 24576, 24576, 98304, 98304};
  static const int      idx[5] = {0, 2, 6, 10, 14};
  Cvt5 jb;
  unsigned cum = 0, dst[5];
  for (int j = 0; j < 5; j++) {
    jb.src[j] = (const float*)d_in[idx[j]];
    jb.cum[j] = cum; jb.dst[j] = cum; dst[j] = cum;
    cum += nel[j];
  }
  jb.cum[5] = cum;
  f16* arena = (f16*)d_ws;
  size_t dynOffB = ((size_t)cum * 2 + 255) & ~(size_t)255;

  // Time-chunk Tc picked from ws_size (full-T preferred; 176.7 MB fits r5's bound).
  static const int candTc[5] = {1024, 512, 256, 128, 64};
  int Tc = 64;
  for (int c = 0; c < 5; c++) {
    size_t nb = dynOffB
              + (size_t)2 * 64 * 1024 * 256 * 2              // z1+z2 f16
              + (size_t)2 * 64 * candTc[c] * 384 * 2         // gi f16
              + (size_t)2 * 64 * 128 * 4;                    // hstate fp32
    if (nb <= ws_size) { Tc = candTc[c]; break; }
  }
  int lTc = 31 - __builtin_clz((unsigned)Tc);
  int nc = 1024 / Tc;

  f16* z1 = (f16*)((char*)d_ws + dynOffB);
  f16* z2 = z1 + (size_t)64 * 1024 * 256;
  f16* gi = z2 + (size_t)64 * 1024 * 256;
  float* hstate = (float*)(gi + (size_t)2 * 64 * Tc * 384);

  const f16 *x16 = arena + dst[0], *w0f = arena + dst[1], *w0b = arena + dst[2],
            *w1f = arena + dst[3], *w1b = arena + dst[4];

  cvt_f16<<<1024, 256, 0, stream>>>(jb, arena, cum);

  dim3 gpb((unsigned)Tc, 2, 1);
  for (int c = 0; c < nc; c++) {
    int t0f = c * Tc, t0b = (nc - 1 - c) * Tc;
    proj_f16<<<gpb, 256, 0, stream>>>(x16, w0f, w0b, bih_l0f, bih_l0b,
                                      bhh_l0f, bhh_l0b, gi, 64, t0f, t0b, lTc);
    gru_mfma<<<8, 512, 0, stream>>>(whh_l0f, whh_l0b, bhh_l0f, bhh_l0b, gi, z1,
                                    hstate, t0f, t0b, c == 0, Tc);
  }
  for (int c = 0; c < nc; c++) {
    int t0f = c * Tc, t0b = (nc - 1 - c) * Tc;
    proj_f16<<<gpb, 256, 0, stream>>>(z1, w1f, w1b, bih_l1f, bih_l1b,
                                      bhh_l1f, bhh_l1b, gi, 256, t0f, t0b, lTc);
    gru_mfma<<<8, 512, 0, stream>>>(whh_l1f, whh_l1b, bhh_l1f, bhh_l1b, gi, z2,
                                    hstate, t0f, t0b, c == 0, Tc);
  }
  pool_heads<<<64, 256, 0, stream>>>(z2, attn_w, attn_b, motor_w, motor_b,
                                     state_w, state_b, motor_k, (float*)d_out);
}

// Round 8
// 2861.143 us; speedup vs baseline: 1.0658x; 1.0222x over previous
//
#include <hip/hip_runtime.h>

// MultiTaskGRUAttn: 2-layer bi-GRU (B=64,T=1024,D=64,H=128) + attn pooling + heads.
// fp32 in/out. f16 activations + f16 MFMA matmuls, fp32 gates + fp32 recurrent h.
// Recurrence: block = 16 samples x 1 dir, 8 waves; wave w owns Whh B-frags for
// N-tiles {w,8+w,16+w} => its C tiles are gates (r,z,n) of units [16w,16w+16).
// h exchanged through LDS in A-FRAGMENT ORDER (conflict-free ds_read_b128);
// gi laid out [dir*4+bg][tt][n384][m16] so recurrence loads are b64-contiguous.

typedef unsigned short u16;
typedef _Float16 f16;
typedef f16  h4  __attribute__((ext_vector_type(4)));
typedef f16  h8  __attribute__((ext_vector_type(8)));
typedef float fv4 __attribute__((ext_vector_type(4)));

#if defined(__has_builtin)
#if __has_builtin(__builtin_amdgcn_exp2f)
#define EXP2F(x) __builtin_amdgcn_exp2f(x)
#endif
#if __has_builtin(__builtin_amdgcn_rcpf)
#define RCPF(x) __builtin_amdgcn_rcpf(x)
#endif
#if __has_builtin(__builtin_amdgcn_mov_dpp)
#define XOR1(v) ((unsigned)__builtin_amdgcn_mov_dpp((int)(v), 0xB1, 0xF, 0xF, true))
#endif
#endif
#ifndef EXP2F
#define EXP2F(x) exp2f(x)
#endif
#ifndef RCPF
#define RCPF(x) (1.f / (x))
#endif
#ifndef XOR1
#define XOR1(v) ((unsigned)__shfl_xor((int)(v), 1))
#endif

// A-frag flat offset for element (m,k) of a 16x128 f16 matrix, frag-ordered for
// mfma_f32_16x16x32_f16 A reads (lane*8 contiguous), XOR-swizzled so the
// gate-phase paired writes are 2-way (free).
__device__ __forceinline__ int fragOff(int m, int k) {
  return ((((k >> 5) << 9) | (((k >> 3) & 3) << 7) | (m << 3) | (k & 7))
          ^ (((m >> 3) & 1) << 4));
}

// ---------------------------------------------------------------------------
struct Cvt5 { const float* src[5]; unsigned dst[5]; unsigned cum[6]; };

__global__ void cvt_f16(Cvt5 jb, f16* __restrict__ arena, unsigned total) {
  unsigned stride = gridDim.x * blockDim.x;
  for (unsigned idx = blockIdx.x * blockDim.x + threadIdx.x; idx < total; idx += stride) {
    int j = 0;
    while (idx >= jb.cum[j + 1]) j++;
    arena[jb.dst[j] + (idx - jb.cum[j])] = (f16)jb.src[j][idx - jb.cum[j]];
  }
}

// ---------------------------------------------------------------------------
// Input projection. Row mapping: ml = tt*64 + sample (grid.x = Tc covers tt).
// Wave wv owns samples [16wv,16wv+16) = batch-group bg=wv; 24 N-tiles.
// Epilogue: b64 stores of 4 samples into gi[(dir*4+bg)][tt][n][m16].
// bias_eff = bih + (n<256 ? bhh : 0) (r,z recurrent biases folded).
// ---------------------------------------------------------------------------
__global__ __launch_bounds__(256) void proj_f16(
    const f16* __restrict__ A, const f16* __restrict__ Wf, const f16* __restrict__ Wb,
    const float* __restrict__ bihf, const float* __restrict__ bihb,
    const float* __restrict__ bhhf, const float* __restrict__ bhhb,
    f16* __restrict__ gi, int K, int t0f, int t0b, int Tc)
{
  int dir = blockIdx.y;
  int tt  = blockIdx.x;
  const f16*   __restrict__ W   = dir ? Wb   : Wf;
  const float* __restrict__ bih = dir ? bihb : bihf;
  const float* __restrict__ bhh = dir ? bhhb : bhhf;
  int t0 = dir ? t0b : t0f;

  int lane = threadIdx.x & 63;
  int wv   = threadIdx.x >> 6;
  int col  = lane & 15;
  int koff = (lane >> 4) * 8;

  int sample = wv * 16 + col;                    // A-frag row m <-> sample
  const f16* ap = A + ((size_t)sample * 1024 + t0 + tt) * K + koff;
  const f16* wp = W + (size_t)col * K + koff;

  fv4 acc[24];
#pragma unroll
  for (int i = 0; i < 24; i++) acc[i] = (fv4){0.f, 0.f, 0.f, 0.f};

  for (int kk = 0; kk < K; kk += 32) {
    h8 a = *(const h8*)(ap + kk);
#pragma unroll
    for (int nt = 0; nt < 24; nt++) {
      h8 bfrag = *(const h8*)(wp + (size_t)nt * 16 * K + kk);
      acc[nt] = __builtin_amdgcn_mfma_f32_16x16x32_f16(a, bfrag, acc[nt], 0, 0, 0);
    }
  }
  int rowq = (lane >> 4) * 4;                    // C rows rowq..rowq+3 = m16 range
  size_t obase = ((size_t)(dir * 4 + wv) * Tc + tt) * 6144;
#pragma unroll
  for (int nt = 0; nt < 24; nt++) {
    int n = nt * 16 + col;
    float bs = bih[n] + ((n < 256) ? bhh[n] : 0.f);
    h4 v = {(f16)(acc[nt][0] + bs), (f16)(acc[nt][1] + bs),
            (f16)(acc[nt][2] + bs), (f16)(acc[nt][3] + bs)};
    *(h4*)(gi + obase + (size_t)n * 16 + rowq) = v;
  }
}

// ---------------------------------------------------------------------------
// Batched-MFMA GRU recurrence. grid 8: dir = blk>>2, bg = blk&3 (16 samples).
// Per step: 12 MFMA/wave (r,z,n x 4 K-frags) on h A-frags from LDS; gate math
// fp32 in the owning lanes; h written back DPP-paired (b32, conflict-free).
// ---------------------------------------------------------------------------
__global__ __launch_bounds__(512) void gru_mfma(
    const float* __restrict__ whhf, const float* __restrict__ whhb,
    const float* __restrict__ bhhf, const float* __restrict__ bhhb,
    const f16* __restrict__ gi, f16* __restrict__ zout,
    float* __restrict__ hstate, int t0f, int t0b, int first, int Tc)
{
  int dir = blockIdx.x >> 2;
  int bg  = blockIdx.x & 3;
  int b0  = bg << 4;
  const float* __restrict__ whh = dir ? whhb : whhf;
  const float* __restrict__ bhh = dir ? bhhb : bhhf;
  int t0 = dir ? t0b : t0f;

  int tid = threadIdx.x;
  int w = tid >> 6, lane = tid & 63;
  int c = lane & 15, q = lane >> 4;
  int n = 16 * w + c;                            // unit owned in gate phase

  // Persistent Whh B-fragments (r7-verified pattern).
  h8 Bf[3][4];
#pragma unroll
  for (int g = 0; g < 3; g++) {
    const float* wrow = whh + (size_t)(g * 128 + n) * 128;
#pragma unroll
    for (int kf = 0; kf < 4; kf++) {
      const float* s = wrow + kf * 32 + q * 8;
      float4 lo = *(const float4*)s, hi = *(const float4*)(s + 4);
      Bf[g][kf] = (h8){(f16)lo.x, (f16)lo.y, (f16)lo.z, (f16)lo.w,
                       (f16)hi.x, (f16)hi.y, (f16)hi.z, (f16)hi.w};
    }
  }
  float bn_ = bhh[256 + n];

  __shared__ __align__(16) f16 hA[2][2048];      // double-buffered A-frag h

  float hreg[4];
#pragma unroll
  for (int r = 0; r < 4; r++) {
    int m16 = q * 4 + r;
    hreg[r] = first ? 0.f : hstate[(size_t)(dir * 64 + b0 + m16) * 128 + n];
    hA[0][fragOff(m16, n)] = (f16)hreg[r];       // scalar init (once)
  }
  __syncthreads();

  int ttF = dir ? (Tc - 1) : 0;
  long gstep = dir ? -6144 : 6144;
  const f16* gbase = gi + ((size_t)(dir * 4 + bg) * Tc + ttF) * 6144
                        + (size_t)n * 16 + q * 4;
  h4 p0[3], p1[3];
#pragma unroll
  for (int g = 0; g < 3; g++) {
    p0[g] = *(const h4*)(gbase + g * 2048);
    p1[g] = *(const h4*)(gbase + gstep + g * 2048);
  }
  unsigned* zo32 = (unsigned*)zout;
  int tcur = t0 + ttF;
  int tinc = dir ? -1 : 1;
  int roff = (lane * 8) ^ (((lane >> 3) & 1) << 4);   // swizzled A-frag read base

  const float L2E = 1.4426950408889634f, L2E2 = 2.885390081777927f;

  for (int s = 0; s < Tc; s++) {
    int cur = s & 1;
    const f16* hb = &hA[cur][0];
    fv4 a0 = {0.f,0.f,0.f,0.f}, a1 = {0.f,0.f,0.f,0.f}, a2 = {0.f,0.f,0.f,0.f};
#pragma unroll
    for (int kf = 0; kf < 4; kf++) {
      h8 a = *(const h8*)(hb + kf * 512 + roff);  // lane-contiguous b128, no conflicts
      a0 = __builtin_amdgcn_mfma_f32_16x16x32_f16(a, Bf[0][kf], a0, 0, 0, 0);
      a1 = __builtin_amdgcn_mfma_f32_16x16x32_f16(a, Bf[1][kf], a1, 0, 0, 0);
      a2 = __builtin_amdgcn_mfma_f32_16x16x32_f16(a, Bf[2][kf], a2, 0, 0, 0);
    }
    h4 p2[3] = {};
    if (s < Tc - 2) {
#pragma unroll
      for (int g = 0; g < 3; g++) p2[g] = *(const h4*)(gbase + 2 * gstep + g * 2048);
    }
    f16* hw = &hA[cur ^ 1][0];
#pragma unroll
    for (int r = 0; r < 4; r++) {
      int m16 = q * 4 + r;
      float ar = (float)p0[0][r] + a0[r];        // bih+bhh(r,z) folded into gi
      float az = (float)p0[1][r] + a1[r];
      float xn = (float)p0[2][r];
      float gn = a2[r] + bn_;
      float rg = RCPF(1.f + EXP2F(-L2E * ar));
      float zg = RCPF(1.f + EXP2F(-L2E * az));
      float npre = fmaf(rg, gn, xn);
      float e = EXP2F(-L2E2 * fabsf(npre));
      float nv = (1.f - e) * RCPF(1.f + e);
      nv = copysignf(nv, npre);
      float h = nv + zg * (hreg[r] - nv);        // (1-z)*n + z*h
      hreg[r] = h;
      f16 hf = (f16)h;
      unsigned short hu; __builtin_memcpy(&hu, &hf, 2);
      unsigned pk = (unsigned)hu | (XOR1(hu) << 16);   // pair (c even | c odd)
      if (!(lane & 1)) {
        ((unsigned*)hw)[fragOff(m16, n) >> 1] = pk;    // 2-way banks = free
        size_t zidx = (((size_t)(b0 + m16) * 1024 + tcur) * 256
                       + (size_t)dir * 128 + n) >> 1;
        zo32[zidx] = pk;
      }
    }
#pragma unroll
    for (int g = 0; g < 3; g++) { p0[g] = p1[g]; p1[g] = p2[g]; }
    gbase += gstep; tcur += tinc;
    __syncthreads();
  }
#pragma unroll
  for (int r = 0; r < 4; r++)
    hstate[(size_t)(dir * 64 + b0 + q * 4 + r) * 128 + n] = hreg[r];
}

// ---------------------------------------------------------------------------
// Attention pooling + heads (f16 z2 in, fp32 out). One block per sample.
// ---------------------------------------------------------------------------
__global__ __launch_bounds__(256) void pool_heads(
    const f16* __restrict__ z2, const float* __restrict__ attn_w, const float* __restrict__ attn_b,
    const float* __restrict__ motor_w, const float* __restrict__ motor_b,
    const float* __restrict__ state_w, const float* __restrict__ state_b,
    const int* __restrict__ motor_k, float* __restrict__ out)
{
  const int T = 1024, D2 = 256;
  int b = blockIdx.x;
  const f16* Z = z2 + (size_t)b * T * D2;
  __shared__ float sc[1024];
  __shared__ float red[8];
  __shared__ float pooled[256];
  int tid = threadIdx.x, lane = tid & 63, wv = tid >> 6;

  float aw0 = attn_w[lane],       aw1 = attn_w[64 + lane];
  float aw2 = attn_w[128 + lane], aw3 = attn_w[192 + lane];
  float ab = attn_b[0];
  for (int t = wv; t < T; t += 4) {
    const f16* zr = Z + (size_t)t * D2;
    float s = (float)zr[lane] * aw0 + (float)zr[64 + lane] * aw1
            + (float)zr[128 + lane] * aw2 + (float)zr[192 + lane] * aw3;
#pragma unroll
    for (int off = 32; off; off >>= 1) s += __shfl_down(s, off);
    if (lane == 0) sc[t] = s + ab;
  }
  __syncthreads();

  float m = -3.0e38f;
  for (int t = tid; t < T; t += 256) m = fmaxf(m, sc[t]);
#pragma unroll
  for (int off = 32; off; off >>= 1) m = fmaxf(m, __shfl_down(m, off));
  if (lane == 0) red[wv] = m;
  __syncthreads();
  m = fmaxf(fmaxf(red[0], red[1]), fmaxf(red[2], red[3]));
  float sum = 0.f;
  for (int t = tid; t < T; t += 256) { float e = __expf(sc[t] - m); sc[t] = e; sum += e; }
#pragma unroll
  for (int off = 32; off; off >>= 1) sum += __shfl_down(sum, off);
  if (lane == 0) red[4 + wv] = sum;
  __syncthreads();
  float S = red[4] + red[5] + red[6] + red[7];
  float inv = 1.f / S;

  float acc = 0.f;
  for (int t = 0; t < T; t++) acc = fmaf(sc[t], (float)Z[(size_t)t * D2 + tid], acc);
  pooled[tid] = acc * inv;
  __syncthreads();

  int o = tid >> 5, sl = tid & 31;
  if (o < 7) {
    int mk = motor_k[b];
    const float* wp; float bias;
    if (o < 5) { wp = motor_w + o * D2;                          bias = motor_b[o]; }
    else       { wp = state_w + ((size_t)mk * 2 + (o - 5)) * D2; bias = state_b[mk * 2 + (o - 5)]; }
    float s = 0.f;
    for (int d = sl; d < D2; d += 32) s += pooled[d] * wp[d];
#pragma unroll
    for (int off = 16; off; off >>= 1) s += __shfl_down(s, off);
    if (sl == 0) {
      float v = s + bias;
      if (o < 5) out[b * 5 + o] = v;
      else       out[320 + b * 2 + (o - 5)] = v;
    }
  }
}

extern "C" void kernel_launch(void* const* d_in, const int* in_sizes, int n_in,
                              void* d_out, int out_size, void* d_ws, size_t ws_size,
                              hipStream_t stream) {
  const int* motor_k = (const int*)d_in[1];
  const float* whh_l0f = (const float*)d_in[3];
  const float* bih_l0f = (const float*)d_in[4];
  const float* bhh_l0f = (const float*)d_in[5];
  const float* whh_l0b = (const float*)d_in[7];
  const float* bih_l0b = (const float*)d_in[8];
  const float* bhh_l0b = (const float*)d_in[9];
  const float* whh_l1f = (const float*)d_in[11];
  const float* bih_l1f = (const float*)d_in[12];
  const float* bhh_l1f = (const float*)d_in[13];
  const float* whh_l1b = (const float*)d_in[15];
  const float* bih_l1b = (const float*)d_in[16];
  const float* bhh_l1b = (const float*)d_in[17];
  const float* attn_w  = (const float*)d_in[18];
  const float* attn_b  = (const float*)d_in[19];
  const float* motor_w = (const float*)d_in[20];
  const float* motor_b = (const float*)d_in[21];
  const float* state_w = (const float*)d_in[22];
  const float* state_b = (const float*)d_in[23];

  // f16 arena: x | wih_l0f | wih_l0b | wih_l1f | wih_l1b
  static const unsigned nel[5] = {4194304, 24576, 24576, 98304, 98304};
  static const int      idx[5] = {0, 2, 6, 10, 14};
  Cvt5 jb;
  unsigned cum = 0, dst[5];
  for (int j = 0; j < 5; j++) {
    jb.src[j] = (const float*)d_in[idx[j]];
    jb.cum[j] = cum; jb.dst[j] = cum; dst[j] = cum;
    cum += nel[j];
  }
  jb.cum[5] = cum;
  f16* arena = (f16*)d_ws;
  size_t dynOffB = ((size_t)cum * 2 + 255) & ~(size_t)255;

  static const int candTc[5] = {1024, 512, 256, 128, 64};
  int Tc = 64;
  for (int c = 0; c < 5; c++) {
    size_t nb = dynOffB
              + (size_t)2 * 64 * 1024 * 256 * 2              // z1+z2 f16
              + (size_t)8 * candTc[c] * 6144 * 2             // gi f16
              + (size_t)2 * 64 * 128 * 4;                    // hstate fp32
    if (nb <= ws_size) { Tc = candTc[c]; break; }
  }
  int nc = 1024 / Tc;

  f16* z1 = (f16*)((char*)d_ws + dynOffB);
  f16* z2 = z1 + (size_t)64 * 1024 * 256;
  f16* gi = z2 + (size_t)64 * 1024 * 256;
  float* hstate = (float*)(gi + (size_t)8 * Tc * 6144);

  const f16 *x16 = arena + dst[0], *w0f = arena + dst[1], *w0b = arena + dst[2],
            *w1f = arena + dst[3], *w1b = arena + dst[4];

  cvt_f16<<<1024, 256, 0, stream>>>(jb, arena, cum);

  dim3 gpb((unsigned)Tc, 2, 1);
  for (int c = 0; c < nc; c++) {
    int t0f = c * Tc, t0b = (nc - 1 - c) * Tc;
    proj_f16<<<gpb, 256, 0, stream>>>(x16, w0f, w0b, bih_l0f, bih_l0b,
                                      bhh_l0f, bhh_l0b, gi, 64, t0f, t0b, Tc);
    gru_mfma<<<8, 512, 0, stream>>>(whh_l0f, whh_l0b, bhh_l0f, bhh_l0b, gi, z1,
                                    hstate, t0f, t0b, c == 0, Tc);
  }
  for (int c = 0; c < nc; c++) {
    int t0f = c * Tc, t0b = (nc - 1 - c) * Tc;
    proj_f16<<<gpb, 256, 0, stream>>>(z1, w1f, w1b, bih_l1f, bih_l1b,
                                      bhh_l1f, bhh_l1b, gi, 256, t0f, t0b, Tc);
    gru_mfma<<<8, 512, 0, stream>>>(whh_l1f, whh_l1b, bhh_l1f, bhh_l1b, gi, z2,
                                    hstate, t0f, t0b, c == 0, Tc);
  }
  pool_heads<<<64, 256, 0, stream>>>(z2, attn_w, attn_b, motor_w, motor_b,
                                     state_w, state_b, motor_k, (float*)d_out);
}

// Round 9
// 2821.216 us; speedup vs baseline: 1.0809x; 1.0142x over previous
//
#include <hip/hip_runtime.h>

// MultiTaskGRUAttn: 2-layer bi-GRU (B=64,T=1024,D=64,H=128) + attn pooling + heads.
// fp32 in/out. f16 activations + f16 MFMA matmuls, fp32 gates + fp32 recurrent h.
// Recurrence: block = 16 samples x 1 dir, 8 waves; wave w owns Whh B-frags for
// N-tiles {w,8+w,16+w} => its C tiles are gates (r,z,n) of units [16w,16w+16).
// h exchanged through LDS in A-FRAGMENT ORDER (conflict-free ds_read_b128);
// gi laid out [dir*4+bg][tt][n384][m16] so recurrence loads are b64-contiguous.
// In-loop barrier is LDS-only (s_waitcnt lgkmcnt(0); s_barrier) so gi prefetch
// loads and zout stores stay in flight across steps (no vmcnt(0) drain).

typedef unsigned short u16;
typedef _Float16 f16;
typedef f16  h4  __attribute__((ext_vector_type(4)));
typedef f16  h8  __attribute__((ext_vector_type(8)));
typedef float fv4 __attribute__((ext_vector_type(4)));

#if defined(__has_builtin)
#if __has_builtin(__builtin_amdgcn_exp2f)
#define EXP2F(x) __builtin_amdgcn_exp2f(x)
#endif
#if __has_builtin(__builtin_amdgcn_rcpf)
#define RCPF(x) __builtin_amdgcn_rcpf(x)
#endif
#if __has_builtin(__builtin_amdgcn_mov_dpp)
#define XOR1(v) ((unsigned)__builtin_amdgcn_mov_dpp((int)(v), 0xB1, 0xF, 0xF, true))
#endif
#endif
#ifndef EXP2F
#define EXP2F(x) exp2f(x)
#endif
#ifndef RCPF
#define RCPF(x) (1.f / (x))
#endif
#ifndef XOR1
#define XOR1(v) ((unsigned)__shfl_xor((int)(v), 1))
#endif

// LDS-only workgroup barrier: drains DS ops, leaves vmcnt outstanding.
__device__ __forceinline__ void wg_barrier_lds() {
  asm volatile("s_waitcnt lgkmcnt(0)\n\ts_barrier" ::: "memory");
}

// A-frag flat offset for element (m,k) of a 16x128 f16 matrix, frag-ordered for
// mfma_f32_16x16x32_f16 A reads (lane*8 contiguous), XOR-swizzled so the
// gate-phase paired writes are 2-way (free).
__device__ __forceinline__ int fragOff(int m, int k) {
  return ((((k >> 5) << 9) | (((k >> 3) & 3) << 7) | (m << 3) | (k & 7))
          ^ (((m >> 3) & 1) << 4));
}

// ---------------------------------------------------------------------------
struct Cvt5 { const float* src[5]; unsigned dst[5]; unsigned cum[6]; };

__global__ void cvt_f16(Cvt5 jb, f16* __restrict__ arena, unsigned total) {
  unsigned stride = gridDim.x * blockDim.x;
  for (unsigned idx = blockIdx.x * blockDim.x + threadIdx.x; idx < total; idx += stride) {
    int j = 0;
    while (idx >= jb.cum[j + 1]) j++;
    arena[jb.dst[j] + (idx - jb.cum[j])] = (f16)jb.src[j][idx - jb.cum[j]];
  }
}

// ---------------------------------------------------------------------------
// Input projection. Row mapping: ml = tt*64 + sample (grid.x = Tc covers tt).
// Wave wv owns samples [16wv,16wv+16) = batch-group bg=wv; 24 N-tiles.
// Epilogue: b64 stores of 4 samples into gi[(dir*4+bg)][tt][n][m16].
// bias_eff = bih + (n<256 ? bhh : 0) (r,z recurrent biases folded).
// ---------------------------------------------------------------------------
__global__ __launch_bounds__(256) void proj_f16(
    const f16* __restrict__ A, const f16* __restrict__ Wf, const f16* __restrict__ Wb,
    const float* __restrict__ bihf, const float* __restrict__ bihb,
    const float* __restrict__ bhhf, const float* __restrict__ bhhb,
    f16* __restrict__ gi, int K, int t0f, int t0b, int Tc)
{
  int dir = blockIdx.y;
  int tt  = blockIdx.x;
  const f16*   __restrict__ W   = dir ? Wb   : Wf;
  const float* __restrict__ bih = dir ? bihb : bihf;
  const float* __restrict__ bhh = dir ? bhhb : bhhf;
  int t0 = dir ? t0b : t0f;

  int lane = threadIdx.x & 63;
  int wv   = threadIdx.x >> 6;
  int col  = lane & 15;
  int koff = (lane >> 4) * 8;

  int sample = wv * 16 + col;                    // A-frag row m <-> sample
  const f16* ap = A + ((size_t)sample * 1024 + t0 + tt) * K + koff;
  const f16* wp = W + (size_t)col * K + koff;

  fv4 acc[24];
#pragma unroll
  for (int i = 0; i < 24; i++) acc[i] = (fv4){0.f, 0.f, 0.f, 0.f};

  for (int kk = 0; kk < K; kk += 32) {
    h8 a = *(const h8*)(ap + kk);
#pragma unroll
    for (int nt = 0; nt < 24; nt++) {
      h8 bfrag = *(const h8*)(wp + (size_t)nt * 16 * K + kk);
      acc[nt] = __builtin_amdgcn_mfma_f32_16x16x32_f16(a, bfrag, acc[nt], 0, 0, 0);
    }
  }
  int rowq = (lane >> 4) * 4;                    // C rows rowq..rowq+3 = m16 range
  size_t obase = ((size_t)(dir * 4 + wv) * Tc + tt) * 6144;
#pragma unroll
  for (int nt = 0; nt < 24; nt++) {
    int n = nt * 16 + col;
    float bs = bih[n] + ((n < 256) ? bhh[n] : 0.f);
    h4 v = {(f16)(acc[nt][0] + bs), (f16)(acc[nt][1] + bs),
            (f16)(acc[nt][2] + bs), (f16)(acc[nt][3] + bs)};
    *(h4*)(gi + obase + (size_t)n * 16 + rowq) = v;
  }
}

// ---------------------------------------------------------------------------
// Batched-MFMA GRU recurrence. grid 8: dir = blk>>2, bg = blk&3 (16 samples).
// Per step: 12 MFMA/wave (r,z,n x 4 K-frags) on h A-frags from LDS; gate math
// fp32 in the owning lanes; h written back DPP-paired (b32, conflict-free).
// launch_bounds(512,2): 256 VGPR budget so Bf/acc/prefetch stay in VGPRs.
// ---------------------------------------------------------------------------
__global__ __launch_bounds__(512, 2) void gru_mfma(
    const float* __restrict__ whhf, const float* __restrict__ whhb,
    const float* __restrict__ bhhf, const float* __restrict__ bhhb,
    const f16* __restrict__ gi, f16* __restrict__ zout,
    float* __restrict__ hstate, int t0f, int t0b, int first, int Tc)
{
  int dir = blockIdx.x >> 2;
  int bg  = blockIdx.x & 3;
  int b0  = bg << 4;
  const float* __restrict__ whh = dir ? whhb : whhf;
  const float* __restrict__ bhh = dir ? bhhb : bhhf;
  int t0 = dir ? t0b : t0f;

  int tid = threadIdx.x;
  int w = tid >> 6, lane = tid & 63;
  int c = lane & 15, q = lane >> 4;
  int n = 16 * w + c;                            // unit owned in gate phase

  // Persistent Whh B-fragments (r7-verified pattern).
  h8 Bf[3][4];
#pragma unroll
  for (int g = 0; g < 3; g++) {
    const float* wrow = whh + (size_t)(g * 128 + n) * 128;
#pragma unroll
    for (int kf = 0; kf < 4; kf++) {
      const float* s = wrow + kf * 32 + q * 8;
      float4 lo = *(const float4*)s, hi = *(const float4*)(s + 4);
      Bf[g][kf] = (h8){(f16)lo.x, (f16)lo.y, (f16)lo.z, (f16)lo.w,
                       (f16)hi.x, (f16)hi.y, (f16)hi.z, (f16)hi.w};
    }
  }
  float bn_ = bhh[256 + n];

  __shared__ __align__(16) f16 hA[2][2048];      // double-buffered A-frag h

  float hreg[4];
#pragma unroll
  for (int r = 0; r < 4; r++) {
    int m16 = q * 4 + r;
    hreg[r] = first ? 0.f : hstate[(size_t)(dir * 64 + b0 + m16) * 128 + n];
    hA[0][fragOff(m16, n)] = (f16)hreg[r];       // scalar init (once)
  }
  __syncthreads();

  int ttF = dir ? (Tc - 1) : 0;
  long gstep = dir ? -6144 : 6144;
  const f16* gbase = gi + ((size_t)(dir * 4 + bg) * Tc + ttF) * 6144
                        + (size_t)n * 16 + q * 4;
  h4 p0[3], p1[3];
#pragma unroll
  for (int g = 0; g < 3; g++) {
    p0[g] = *(const h4*)(gbase + g * 2048);
    p1[g] = *(const h4*)(gbase + gstep + g * 2048);
  }
  unsigned* zo32 = (unsigned*)zout;
  int tcur = t0 + ttF;
  int tinc = dir ? -1 : 1;
  int roff = (lane * 8) ^ (((lane >> 3) & 1) << 4);   // swizzled A-frag read base

  const float L2E = 1.4426950408889634f, L2E2 = 2.885390081777927f;

  for (int s = 0; s < Tc; s++) {
    int cur = s & 1;
    const f16* hb = &hA[cur][0];
    // C init from folded gi (r,z): saves the post-adds; n-gate C starts at 0.
    fv4 a0 = {(float)p0[0][0], (float)p0[0][1], (float)p0[0][2], (float)p0[0][3]};
    fv4 a1 = {(float)p0[1][0], (float)p0[1][1], (float)p0[1][2], (float)p0[1][3]};
    fv4 a2 = {0.f, 0.f, 0.f, 0.f};
#pragma unroll
    for (int kf = 0; kf < 4; kf++) {
      h8 a = *(const h8*)(hb + kf * 512 + roff);  // lane-contiguous b128, no conflicts
      a0 = __builtin_amdgcn_mfma_f32_16x16x32_f16(a, Bf[0][kf], a0, 0, 0, 0);
      a1 = __builtin_amdgcn_mfma_f32_16x16x32_f16(a, Bf[1][kf], a1, 0, 0, 0);
      a2 = __builtin_amdgcn_mfma_f32_16x16x32_f16(a, Bf[2][kf], a2, 0, 0, 0);
    }
    h4 p2[3] = {};
    if (s < Tc - 2) {
#pragma unroll
      for (int g = 0; g < 3; g++) p2[g] = *(const h4*)(gbase + 2 * gstep + g * 2048);
    }
    f16* hw = &hA[cur ^ 1][0];
#pragma unroll
    for (int r = 0; r < 4; r++) {
      int m16 = q * 4 + r;
      float ar = a0[r];                          // bih+bhh(r,z) folded via C-init
      float az = a1[r];
      float xn = (float)p0[2][r];
      float gn = a2[r] + bn_;
      float rg = RCPF(1.f + EXP2F(-L2E * ar));
      float zg = RCPF(1.f + EXP2F(-L2E * az));
      float npre = fmaf(rg, gn, xn);
      float e = EXP2F(-L2E2 * fabsf(npre));
      float nv = (1.f - e) * RCPF(1.f + e);
      nv = copysignf(nv, npre);
      float h = nv + zg * (hreg[r] - nv);        // (1-z)*n + z*h
      hreg[r] = h;
      f16 hf = (f16)h;
      unsigned short hu; __builtin_memcpy(&hu, &hf, 2);
      unsigned pk = (unsigned)hu | (XOR1(hu) << 16);   // pair (c even | c odd)
      if (!(lane & 1)) {
        ((unsigned*)hw)[fragOff(m16, n) >> 1] = pk;    // 2-way banks = free
        size_t zidx = (((size_t)(b0 + m16) * 1024 + tcur) * 256
                       + (size_t)dir * 128 + n) >> 1;
        zo32[zidx] = pk;
      }
    }
#pragma unroll
    for (int g = 0; g < 3; g++) { p0[g] = p1[g]; p1[g] = p2[g]; }
    gbase += gstep; tcur += tinc;
    wg_barrier_lds();                            // LDS-only drain: vmcnt stays in flight
  }
#pragma unroll
  for (int r = 0; r < 4; r++)
    hstate[(size_t)(dir * 64 + b0 + q * 4 + r) * 128 + n] = hreg[r];
}

// ---------------------------------------------------------------------------
// Attention pooling + heads (f16 z2 in, fp32 out). One block per sample.
// ---------------------------------------------------------------------------
__global__ __launch_bounds__(256) void pool_heads(
    const f16* __restrict__ z2, const float* __restrict__ attn_w, const float* __restrict__ attn_b,
    const float* __restrict__ motor_w, const float* __restrict__ motor_b,
    const float* __restrict__ state_w, const float* __restrict__ state_b,
    const int* __restrict__ motor_k, float* __restrict__ out)
{
  const int T = 1024, D2 = 256;
  int b = blockIdx.x;
  const f16* Z = z2 + (size_t)b * T * D2;
  __shared__ float sc[1024];
  __shared__ float red[8];
  __shared__ float pooled[256];
  int tid = threadIdx.x, lane = tid & 63, wv = tid >> 6;

  float aw0 = attn_w[lane],       aw1 = attn_w[64 + lane];
  float aw2 = attn_w[128 + lane], aw3 = attn_w[192 + lane];
  float ab = attn_b[0];
  for (int t = wv; t < T; t += 4) {
    const f16* zr = Z + (size_t)t * D2;
    float s = (float)zr[lane] * aw0 + (float)zr[64 + lane] * aw1
            + (float)zr[128 + lane] * aw2 + (float)zr[192 + lane] * aw3;
#pragma unroll
    for (int off = 32; off; off >>= 1) s += __shfl_down(s, off);
    if (lane == 0) sc[t] = s + ab;
  }
  __syncthreads();

  float m = -3.0e38f;
  for (int t = tid; t < T; t += 256) m = fmaxf(m, sc[t]);
#pragma unroll
  for (int off = 32; off; off >>= 1) m = fmaxf(m, __shfl_down(m, off));
  if (lane == 0) red[wv] = m;
  __syncthreads();
  m = fmaxf(fmaxf(red[0], red[1]), fmaxf(red[2], red[3]));
  float sum = 0.f;
  for (int t = tid; t < T; t += 256) { float e = __expf(sc[t] - m); sc[t] = e; sum += e; }
#pragma unroll
  for (int off = 32; off; off >>= 1) sum += __shfl_down(sum, off);
  if (lane == 0) red[4 + wv] = sum;
  __syncthreads();
  float S = red[4] + red[5] + red[6] + red[7];
  float inv = 1.f / S;

  float acc = 0.f;
  for (int t = 0; t < T; t++) acc = fmaf(sc[t], (float)Z[(size_t)t * D2 + tid], acc);
  pooled[tid] = acc * inv;
  __syncthreads();

  int o = tid >> 5, sl = tid & 31;
  if (o < 7) {
    int mk = motor_k[b];
    const float* wp; float bias;
    if (o < 5) { wp = motor_w + o * D2;                          bias = motor_b[o]; }
    else       { wp = state_w + ((size_t)mk * 2 + (o - 5)) * D2; bias = state_b[mk * 2 + (o - 5)]; }
    float s = 0.f;
    for (int d = sl; d < D2; d += 32) s += pooled[d] * wp[d];
#pragma unroll
    for (int off = 16; off; off >>= 1) s += __shfl_down(s, off);
    if (sl == 0) {
      float v = s + bias;
      if (o < 5) out[b * 5 + o] = v;
      else       out[320 + b * 2 + (o - 5)] = v;
    }
  }
}

extern "C" void kernel_launch(void* const* d_in, const int* in_sizes, int n_in,
                              void* d_out, int out_size, void* d_ws, size_t ws_size,
                              hipStream_t stream) {
  const int* motor_k = (const int*)d_in[1];
  const float* whh_l0f = (const float*)d_in[3];
  const float* bih_l0f = (const float*)d_in[4];
  const float* bhh_l0f = (const float*)d_in[5];
  const float* whh_l0b = (const float*)d_in[7];
  const float* bih_l0b = (const float*)d_in[8];
  const float* bhh_l0b = (const float*)d_in[9];
  const float* whh_l1f = (const float*)d_in[11];
  const float* bih_l1f = (const float*)d_in[12];
  const float* bhh_l1f = (const float*)d_in[13];
  const float* whh_l1b = (const float*)d_in[15];
  const float* bih_l1b = (const float*)d_in[16];
  const float* bhh_l1b = (const float*)d_in[17];
  const float* attn_w  = (const float*)d_in[18];
  const float* attn_b  = (const float*)d_in[19];
  const float* motor_w = (const float*)d_in[20];
  const float* motor_b = (const float*)d_in[21];
  const float* state_w = (const float*)d_in[22];
  const float* state_b = (const float*)d_in[23];

  // f16 arena: x | wih_l0f | wih_l0b | wih_l1f | wih_l1b
  static const unsigned nel[5] = {4194304, 24576, 24576, 98304, 98304};
  static const int      idx[5] = {0, 2, 6, 10, 14};
  Cvt5 jb;
  unsigned cum = 0, dst[5];
  for (int j = 0; j < 5; j++) {
    jb.src[j] = (const float*)d_in[idx[j]];
    jb.cum[j] = cum; jb.dst[j] = cum; dst[j] = cum;
    cum += nel[j];
  }
  jb.cum[5] = cum;
  f16* arena = (f16*)d_ws;
  size_t dynOffB = ((size_t)cum * 2 + 255) & ~(size_t)255;

  static const int candTc[5] = {1024, 512, 256, 128, 64};
  int Tc = 64;
  for (int c = 0; c < 5; c++) {
    size_t nb = dynOffB
              + (size_t)2 * 64 * 1024 * 256 * 2              // z1+z2 f16
              + (size_t)8 * candTc[c] * 6144 * 2             // gi f16
              + (size_t)2 * 64 * 128 * 4;                    // hstate fp32
    if (nb <= ws_size) { Tc = candTc[c]; break; }
  }
  int nc = 1024 / Tc;

  f16* z1 = (f16*)((char*)d_ws + dynOffB);
  f16* z2 = z1 + (size_t)64 * 1024 * 256;
  f16* gi = z2 + (size_t)64 * 1024 * 256;
  float* hstate = (float*)(gi + (size_t)8 * Tc * 6144);

  const f16 *x16 = arena + dst[0], *w0f = arena + dst[1], *w0b = arena + dst[2],
            *w1f = arena + dst[3], *w1b = arena + dst[4];

  cvt_f16<<<1024, 256, 0, stream>>>(jb, arena, cum);

  dim3 gpb((unsigned)Tc, 2, 1);
  for (int c = 0; c < nc; c++) {
    int t0f = c * Tc, t0b = (nc - 1 - c) * Tc;
    proj_f16<<<gpb, 256, 0, stream>>>(x16, w0f, w0b, bih_l0f, bih_l0b,
                                      bhh_l0f, bhh_l0b, gi, 64, t0f, t0b, Tc);
    gru_mfma<<<8, 512, 0, stream>>>(whh_l0f, whh_l0b, bhh_l0f, bhh_l0b, gi, z1,
                                    hstate, t0f, t0b, c == 0, Tc);
  }
  for (int c = 0; c < nc; c++) {
    int t0f = c * Tc, t0b = (nc - 1 - c) * Tc;
    proj_f16<<<gpb, 256, 0, stream>>>(z1, w1f, w1b, bih_l1f, bih_l1b,
                                      bhh_l1f, bhh_l1b, gi, 256, t0f, t0b, Tc);
    gru_mfma<<<8, 512, 0, stream>>>(whh_l1f, whh_l1b, bhh_l1f, bhh_l1b, gi, z2,
                                    hstate, t0f, t0b, c == 0, Tc);
  }
  pool_heads<<<64, 256, 0, stream>>>(z2, attn_w, attn_b, motor_w, motor_b,
                                     state_w, state_b, motor_k, (float*)d_out);
}

// Round 10
// 2751.791 us; speedup vs baseline: 1.1082x; 1.0252x over previous
//
#include <hip/hip_runtime.h>

// MultiTaskGRUAttn: 2-layer bi-GRU (B=64,T=1024,D=64,H=128) + attn pooling + heads.
// fp32 in/out. f16 activations + f16 MFMA matmuls, fp32 gates + fp32 recurrent h.
// Recurrence: block = 16 samples x 1 dir, 8 waves; wave w owns Whh B-frags for
// N-tiles {w,8+w,16+w} => its C tiles are gates (r,z,n) of units [16w,16w+16).
// h exchanged through LDS in A-FRAGMENT ORDER (conflict-free ds_read_b128);
// gi laid out [dir*4+bg][tt][n384][m16] so recurrence loads are b64-contiguous.
// r10: gate phase stripped to minimum VALU — b16 scalar writes (no DPP/exec
// masks), 32-bit offset addressing, biases folded into MFMA C-init.

typedef unsigned short u16;
typedef _Float16 f16;
typedef f16  h4  __attribute__((ext_vector_type(4)));
typedef f16  h8  __attribute__((ext_vector_type(8)));
typedef float fv4 __attribute__((ext_vector_type(4)));

#if defined(__has_builtin)
#if __has_builtin(__builtin_amdgcn_exp2f)
#define EXP2F(x) __builtin_amdgcn_exp2f(x)
#endif
#if __has_builtin(__builtin_amdgcn_rcpf)
#define RCPF(x) __builtin_amdgcn_rcpf(x)
#endif
#endif
#ifndef EXP2F
#define EXP2F(x) exp2f(x)
#endif
#ifndef RCPF
#define RCPF(x) (1.f / (x))
#endif

// A-frag flat offset for element (m,k) of a 16x128 f16 matrix, frag-ordered for
// mfma_f32_16x16x32_f16 A reads (lane*8 contiguous), XOR-swizzled so the
// gate-phase writes stay <=2-way banked (free).
__device__ __forceinline__ int fragOff(int m, int k) {
  return ((((k >> 5) << 9) | (((k >> 3) & 3) << 7) | (m << 3) | (k & 7))
          ^ (((m >> 3) & 1) << 4));
}

// ---------------------------------------------------------------------------
struct Cvt5 { const float* src[5]; unsigned dst[5]; unsigned cum[6]; };

__global__ void cvt_f16(Cvt5 jb, f16* __restrict__ arena, unsigned total) {
  unsigned stride = gridDim.x * blockDim.x;
  for (unsigned idx = blockIdx.x * blockDim.x + threadIdx.x; idx < total; idx += stride) {
    int j = 0;
    while (idx >= jb.cum[j + 1]) j++;
    arena[jb.dst[j] + (idx - jb.cum[j])] = (f16)jb.src[j][idx - jb.cum[j]];
  }
}

// ---------------------------------------------------------------------------
// Input projection. Row mapping: ml = tt*64 + sample (grid.x = Tc covers tt).
// Wave wv owns samples [16wv,16wv+16) = batch-group bg=wv; 24 N-tiles.
// Epilogue: b64 stores of 4 samples into gi[(dir*4+bg)][tt][n][m16].
// bias_eff = bih + (n<256 ? bhh : 0) (r,z recurrent biases folded).
// ---------------------------------------------------------------------------
__global__ __launch_bounds__(256) void proj_f16(
    const f16* __restrict__ A, const f16* __restrict__ Wf, const f16* __restrict__ Wb,
    const float* __restrict__ bihf, const float* __restrict__ bihb,
    const float* __restrict__ bhhf, const float* __restrict__ bhhb,
    f16* __restrict__ gi, int K, int t0f, int t0b, int Tc)
{
  int dir = blockIdx.y;
  int tt  = blockIdx.x;
  const f16*   __restrict__ W   = dir ? Wb   : Wf;
  const float* __restrict__ bih = dir ? bihb : bihf;
  const float* __restrict__ bhh = dir ? bhhb : bhhf;
  int t0 = dir ? t0b : t0f;

  int lane = threadIdx.x & 63;
  int wv   = threadIdx.x >> 6;
  int col  = lane & 15;
  int koff = (lane >> 4) * 8;

  int sample = wv * 16 + col;                    // A-frag row m <-> sample
  const f16* ap = A + ((size_t)sample * 1024 + t0 + tt) * K + koff;
  const f16* wp = W + (size_t)col * K + koff;

  fv4 acc[24];
#pragma unroll
  for (int i = 0; i < 24; i++) acc[i] = (fv4){0.f, 0.f, 0.f, 0.f};

  for (int kk = 0; kk < K; kk += 32) {
    h8 a = *(const h8*)(ap + kk);
#pragma unroll
    for (int nt = 0; nt < 24; nt++) {
      h8 bfrag = *(const h8*)(wp + (size_t)nt * 16 * K + kk);
      acc[nt] = __builtin_amdgcn_mfma_f32_16x16x32_f16(a, bfrag, acc[nt], 0, 0, 0);
    }
  }
  int rowq = (lane >> 4) * 4;                    // C rows rowq..rowq+3 = m16 range
  size_t obase = ((size_t)(dir * 4 + wv) * Tc + tt) * 6144;
#pragma unroll
  for (int nt = 0; nt < 24; nt++) {
    int n = nt * 16 + col;
    float bs = bih[n] + ((n < 256) ? bhh[n] : 0.f);
    h4 v = {(f16)(acc[nt][0] + bs), (f16)(acc[nt][1] + bs),
            (f16)(acc[nt][2] + bs), (f16)(acc[nt][3] + bs)};
    *(h4*)(gi + obase + (size_t)n * 16 + rowq) = v;
  }
}

// ---------------------------------------------------------------------------
// Batched-MFMA GRU recurrence. grid 8: dir = blk>>2, bg = blk&3 (16 samples).
// Per step: 12 MFMA/wave (r,z,n x 4 K-frags) on h A-frags from LDS; gate math
// fp32 in the owning lanes; h/zout written as b16 scalars (all lanes).
// launch_bounds(512,2): 256 VGPR budget so Bf/acc/prefetch stay in registers.
// ---------------------------------------------------------------------------
__global__ __launch_bounds__(512, 2) void gru_mfma(
    const float* __restrict__ whhf, const float* __restrict__ whhb,
    const float* __restrict__ bhhf, const float* __restrict__ bhhb,
    const f16* __restrict__ gi, f16* __restrict__ zout,
    float* __restrict__ hstate, int t0f, int t0b, int first, int Tc)
{
  int dir = blockIdx.x >> 2;
  int bg  = blockIdx.x & 3;
  int b0  = bg << 4;
  const float* __restrict__ whh = dir ? whhb : whhf;
  const float* __restrict__ bhh = dir ? bhhb : bhhf;
  int t0 = dir ? t0b : t0f;

  int tid = threadIdx.x;
  int w = tid >> 6, lane = tid & 63;
  int c = lane & 15, q = lane >> 4;
  int n = 16 * w + c;                            // unit owned in gate phase

  // Persistent Whh B-fragments (r7-verified pattern).
  h8 Bf[3][4];
#pragma unroll
  for (int g = 0; g < 3; g++) {
    const float* wrow = whh + (size_t)(g * 128 + n) * 128;
#pragma unroll
    for (int kf = 0; kf < 4; kf++) {
      const float* s = wrow + kf * 32 + q * 8;
      float4 lo = *(const float4*)s, hi = *(const float4*)(s + 4);
      Bf[g][kf] = (h8){(f16)lo.x, (f16)lo.y, (f16)lo.z, (f16)lo.w,
                       (f16)hi.x, (f16)hi.y, (f16)hi.z, (f16)hi.w};
    }
  }
  float bn_ = bhh[256 + n];

  __shared__ __align__(16) f16 hA[2][2048];      // double-buffered A-frag h

  float hreg[4];
#pragma unroll
  for (int r = 0; r < 4; r++) {
    int m16 = q * 4 + r;
    hreg[r] = first ? 0.f : hstate[(size_t)(dir * 64 + b0 + m16) * 128 + n];
    hA[0][fragOff(m16, n)] = (f16)hreg[r];       // scalar init (once)
  }
  __syncthreads();

  int ttF = dir ? (Tc - 1) : 0;
  int gstep32 = dir ? -6144 : 6144;              // 32-bit offset addressing
  int zstep32 = dir ? -256 : 256;
  int goff = ((dir * 4 + bg) * Tc + ttF) * 6144 + n * 16 + q * 4;
  int zoff = ((b0 + q * 4) * 1024 + (t0 + ttF)) * 256 + dir * 128 + n;
  const int ZR = 1024 * 256;                     // zout r-stride (sample stride)

  h4 p0[3], p1[3];
#pragma unroll
  for (int g = 0; g < 3; g++) {
    p0[g] = *(const h4*)(gi + goff + g * 2048);
    p1[g] = *(const h4*)(gi + goff + gstep32 + g * 2048);
  }
  int roff = (lane * 8) ^ (((lane >> 3) & 1) << 4);   // swizzled A-frag read base

  const float L2E = 1.4426950408889634f, L2E2 = 2.885390081777927f;

#pragma unroll 2
  for (int s = 0; s < Tc; s++) {
    int cur = s & 1;
    // prefetch gi for step s+2 first (loads fly during MFMA phase)
    h4 p2[3] = {};
    if (s < Tc - 2) {
      int g2 = goff + 2 * gstep32;
#pragma unroll
      for (int g = 0; g < 3; g++) p2[g] = *(const h4*)(gi + g2 + g * 2048);
    }
    const f16* hb = &hA[cur][0];
    // C init from folded gi (r,z) and bn_ (n): no post-adds.
    fv4 a0 = {(float)p0[0][0], (float)p0[0][1], (float)p0[0][2], (float)p0[0][3]};
    fv4 a1 = {(float)p0[1][0], (float)p0[1][1], (float)p0[1][2], (float)p0[1][3]};
    fv4 a2 = {bn_, bn_, bn_, bn_};
#pragma unroll
    for (int kf = 0; kf < 4; kf++) {
      h8 a = *(const h8*)(hb + kf * 512 + roff);  // lane-contiguous b128, no conflicts
      a0 = __builtin_amdgcn_mfma_f32_16x16x32_f16(a, Bf[0][kf], a0, 0, 0, 0);
      a1 = __builtin_amdgcn_mfma_f32_16x16x32_f16(a, Bf[1][kf], a1, 0, 0, 0);
      a2 = __builtin_amdgcn_mfma_f32_16x16x32_f16(a, Bf[2][kf], a2, 0, 0, 0);
    }
    f16* hw = &hA[cur ^ 1][0];
#pragma unroll
    for (int r = 0; r < 4; r++) {
      int m16 = q * 4 + r;
      float xn = (float)p0[2][r];
      float rg = RCPF(1.f + EXP2F(-L2E * a0[r]));
      float zg = RCPF(1.f + EXP2F(-L2E * a1[r]));
      float npre = fmaf(rg, a2[r], xn);
      float e = EXP2F(-L2E2 * fabsf(npre));
      float nv = (1.f - e) * RCPF(1.f + e);
      nv = copysignf(nv, npre);
      float h = nv + zg * (hreg[r] - nv);        // (1-z)*n + z*h
      hreg[r] = h;
      f16 hf = (f16)h;
      hw[fragOff(m16, n)] = hf;                  // b16, <=2-way banks (free)
      zout[zoff + r * ZR] = hf;                  // b16 scalar store (saddr+voffset)
    }
#pragma unroll
    for (int g = 0; g < 3; g++) { p0[g] = p1[g]; p1[g] = p2[g]; }
    goff += gstep32; zoff += zstep32;
    __syncthreads();
  }
#pragma unroll
  for (int r = 0; r < 4; r++)
    hstate[(size_t)(dir * 64 + b0 + q * 4 + r) * 128 + n] = hreg[r];
}

// ---------------------------------------------------------------------------
// Attention pooling + heads (f16 z2 in, fp32 out). One block per sample.
// ---------------------------------------------------------------------------
__global__ __launch_bounds__(256) void pool_heads(
    const f16* __restrict__ z2, const float* __restrict__ attn_w, const float* __restrict__ attn_b,
    const float* __restrict__ motor_w, const float* __restrict__ motor_b,
    const float* __restrict__ state_w, const float* __restrict__ state_b,
    const int* __restrict__ motor_k, float* __restrict__ out)
{
  const int T = 1024, D2 = 256;
  int b = blockIdx.x;
  const f16* Z = z2 + (size_t)b * T * D2;
  __shared__ float sc[1024];
  __shared__ float red[8];
  __shared__ float pooled[256];
  int tid = threadIdx.x, lane = tid & 63, wv = tid >> 6;

  float aw0 = attn_w[lane],       aw1 = attn_w[64 + lane];
  float aw2 = attn_w[128 + lane], aw3 = attn_w[192 + lane];
  float ab = attn_b[0];
  for (int t = wv; t < T; t += 4) {
    const f16* zr = Z + (size_t)t * D2;
    float s = (float)zr[lane] * aw0 + (float)zr[64 + lane] * aw1
            + (float)zr[128 + lane] * aw2 + (float)zr[192 + lane] * aw3;
#pragma unroll
    for (int off = 32; off; off >>= 1) s += __shfl_down(s, off);
    if (lane == 0) sc[t] = s + ab;
  }
  __syncthreads();

  float m = -3.0e38f;
  for (int t = tid; t < T; t += 256) m = fmaxf(m, sc[t]);
#pragma unroll
  for (int off = 32; off; off >>= 1) m = fmaxf(m, __shfl_down(m, off));
  if (lane == 0) red[wv] = m;
  __syncthreads();
  m = fmaxf(fmaxf(red[0], red[1]), fmaxf(red[2], red[3]));
  float sum = 0.f;
  for (int t = tid; t < T; t += 256) { float e = __expf(sc[t] - m); sc[t] = e; sum += e; }
#pragma unroll
  for (int off = 32; off; off >>= 1) sum += __shfl_down(sum, off);
  if (lane == 0) red[4 + wv] = sum;
  __syncthreads();
  float S = red[4] + red[5] + red[6] + red[7];
  float inv = 1.f / S;

  float acc = 0.f;
  for (int t = 0; t < T; t++) acc = fmaf(sc[t], (float)Z[(size_t)t * D2 + tid], acc);
  pooled[tid] = acc * inv;
  __syncthreads();

  int o = tid >> 5, sl = tid & 31;
  if (o < 7) {
    int mk = motor_k[b];
    const float* wp; float bias;
    if (o < 5) { wp = motor_w + o * D2;                          bias = motor_b[o]; }
    else       { wp = state_w + ((size_t)mk * 2 + (o - 5)) * D2; bias = state_b[mk * 2 + (o - 5)]; }
    float s = 0.f;
    for (int d = sl; d < D2; d += 32) s += pooled[d] * wp[d];
#pragma unroll
    for (int off = 16; off; off >>= 1) s += __shfl_down(s, off);
    if (sl == 0) {
      float v = s + bias;
      if (o < 5) out[b * 5 + o] = v;
      else       out[320 + b * 2 + (o - 5)] = v;
    }
  }
}

extern "C" void kernel_launch(void* const* d_in, const int* in_sizes, int n_in,
                              void* d_out, int out_size, void* d_ws, size_t ws_size,
                              hipStream_t stream) {
  const int* motor_k = (const int*)d_in[1];
  const float* whh_l0f = (const float*)d_in[3];
  const float* bih_l0f = (const float*)d_in[4];
  const float* bhh_l0f = (const float*)d_in[5];
  const float* whh_l0b = (const float*)d_in[7];
  const float* bih_l0b = (const float*)d_in[8];
  const float* bhh_l0b = (const float*)d_in[9];
  const float* whh_l1f = (const float*)d_in[11];
  const float* bih_l1f = (const float*)d_in[12];
  const float* bhh_l1f = (const float*)d_in[13];
  const float* whh_l1b = (const float*)d_in[15];
  const float* bih_l1b = (const float*)d_in[16];
  const float* bhh_l1b = (const float*)d_in[17];
  const float* attn_w  = (const float*)d_in[18];
  const float* attn_b  = (const float*)d_in[19];
  const float* motor_w = (const float*)d_in[20];
  const float* motor_b = (const float*)d_in[21];
  const float* state_w = (const float*)d_in[22];
  const float* state_b = (const float*)d_in[23];

  // f16 arena: x | wih_l0f | wih_l0b | wih_l1f | wih_l1b
  static const unsigned nel[5] = {4194304, 24576, 24576, 98304, 98304};
  static const int      idx[5] = {0, 2, 6, 10, 14};
  Cvt5 jb;
  unsigned cum = 0, dst[5];
  for (int j = 0; j < 5; j++) {
    jb.src[j] = (const float*)d_in[idx[j]];
    jb.cum[j] = cum; jb.dst[j] = cum; dst[j] = cum;
    cum += nel[j];
  }
  jb.cum[5] = cum;
  f16* arena = (f16*)d_ws;
  size_t dynOffB = ((size_t)cum * 2 + 255) & ~(size_t)255;

  static const int candTc[5] = {1024, 512, 256, 128, 64};
  int Tc = 64;
  for (int c = 0; c < 5; c++) {
    size_t nb = dynOffB
              + (size_t)2 * 64 * 1024 * 256 * 2              // z1+z2 f16
              + (size_t)8 * candTc[c] * 6144 * 2             // gi f16
              + (size_t)2 * 64 * 128 * 4;                    // hstate fp32
    if (nb <= ws_size) { Tc = candTc[c]; break; }
  }
  int nc = 1024 / Tc;

  f16* z1 = (f16*)((char*)d_ws + dynOffB);
  f16* z2 = z1 + (size_t)64 * 1024 * 256;
  f16* gi = z2 + (size_t)64 * 1024 * 256;
  float* hstate = (float*)(gi + (size_t)8 * Tc * 6144);

  const f16 *x16 = arena + dst[0], *w0f = arena + dst[1], *w0b = arena + dst[2],
            *w1f = arena + dst[3], *w1b = arena + dst[4];

  cvt_f16<<<1024, 256, 0, stream>>>(jb, arena, cum);

  dim3 gpb((unsigned)Tc, 2, 1);
  for (int c = 0; c < nc; c++) {
    int t0f = c * Tc, t0b = (nc - 1 - c) * Tc;
    proj_f16<<<gpb, 256, 0, stream>>>(x16, w0f, w0b, bih_l0f, bih_l0b,
                                      bhh_l0f, bhh_l0b, gi, 64, t0f, t0b, Tc);
    gru_mfma<<<8, 512, 0, stream>>>(whh_l0f, whh_l0b, bhh_l0f, bhh_l0b, gi, z1,
                                    hstate, t0f, t0b, c == 0, Tc);
  }
  for (int c = 0; c < nc; c++) {
    int t0f = c * Tc, t0b = (nc - 1 - c) * Tc;
    proj_f16<<<gpb, 256, 0, stream>>>(z1, w1f, w1b, bih_l1f, bih_l1b,
                                      bhh_l1f, bhh_l1b, gi, 256, t0f, t0b, Tc);
    gru_mfma<<<8, 512, 0, stream>>>(whh_l1f, whh_l1b, bhh_l1f, bhh_l1b, gi, z2,
                                    hstate, t0f, t0b, c == 0, Tc);
  }
  pool_heads<<<64, 256, 0, stream>>>(z2, attn_w, attn_b, motor_w, motor_b,
                                     state_w, state_b, motor_k, (float*)d_out);
}